// Round 9
// baseline (134.998 us; speedup 1.0000x reference)
//
#include <hip/hip_runtime.h>

// ---------------------------------------------------------------------------
// R22 = R21 + conv2/conv3 weights staged in LDS (the ONE change).
// Mechanism: s_load weights inside the conv loops complete out-of-order on
// lgkmcnt -> every weight use forces s_waitcnt lgkmcnt(0), which also drains
// pipelined ds_reads -> no cross-iteration pipelining (15 serialized
// latency exposures per conv). With weights in LDS the lgkm queue is
// in-order -> compiler emits partial lgkmcnt(N) waits -> iteration i+1's
// loads issue behind iteration i's MACs. R16's catastrophic version of this
// idea died of register-array scratch spill (3 confounded changes), not of
// LDS-weights itself: here weights are read per-kx (<=16 transient VGPRs),
// block shape unchanged (256 thr), conv1 stays on the SMEM tap-outer path.
// LDS 15.9 -> 22.2 KB => 7 blocks/CU. Weight reads are wave-uniform ->
// broadcast, conflict-free.
// Cardinal cubic B-spline: basis_j(x) = B3(u - j), u = 2.5x+5.5 (4 taps).
// ---------------------------------------------------------------------------

typedef _Float16 h2 __attribute__((ext_vector_type(2)));

__device__ __forceinline__ h2 u2h(unsigned int u) {
  union { unsigned int x; h2 h; } v; v.x = u; return v.h;
}
__device__ __forceinline__ unsigned short f2h_bits(float x) {
  union { _Float16 h; unsigned short u; } v; v.h = (_Float16)x; return v.u;
}
__device__ __forceinline__ float h2f(unsigned short u) {
  union { unsigned short u; _Float16 h; } v; v.u = u; return (float)v.h;
}
__device__ __forceinline__ unsigned int pack2h(float a, float b) {
  return (unsigned int)f2h_bits(a) | ((unsigned int)f2h_bits(b) << 16);
}
__device__ __forceinline__ float fdot2(h2 a, h2 b, float c) {
  return __builtin_amdgcn_fdot2(a, b, c, false);
}

// Basis window (8 f16 packed in uint4) + silu, all in registers.
__device__ __forceinline__ void featurize_regs(float v, uint4& bs, float& silu) {
  silu = v * __builtin_amdgcn_rcpf(1.0f + __expf(-v));
  bs.x = 0u; bs.y = 0u; bs.z = 0u; bs.w = 0u;
  float u = fmaf(v, 2.5f, 5.5f);
  if (u >= 0.0f && u < 11.0f) {
    float tf = floorf(u);
    float f = u - tf, f2 = f * f, f3 = f2 * f, om = 1.0f - f;
    const float c6 = 1.0f / 6.0f;
    float w0 = om * om * om * c6;
    float w1 = (3.0f * f3 - 6.0f * f2 + 4.0f) * c6;
    float w2 = (-3.0f * f3 + 3.0f * f2 + 3.0f * f + 1.0f) * c6;
    float w3 = f3 * c6;
    unsigned long long w01 =
        (unsigned long long)f2h_bits(w0) |
        ((unsigned long long)f2h_bits(w1) << 16) |
        ((unsigned long long)f2h_bits(w2) << 32) |
        ((unsigned long long)f2h_bits(w3) << 48);
    int t = (int)tf;                 // 0..10; window starts at slot t-3
    int s = 16 * t - 48;             // bit shift into 128-bit field
    unsigned long long lo, hi;
    if (s >= 0) {
      lo = (s < 64) ? (w01 << s) : 0ull;
      hi = (s == 0) ? 0ull : ((s < 64) ? (w01 >> (64 - s)) : (w01 << (s - 64)));
    } else {
      lo = w01 >> (-s);
      hi = 0ull;
    }
    bs.x = (unsigned int)lo; bs.y = (unsigned int)(lo >> 32);
    bs.z = (unsigned int)hi; bs.w = (unsigned int)(hi >> 32);
  }
}

// KAN 3x3-conv accumulation, one position per lane, NO output channels.
// wS/wB now point into LDS ([cky][kx][j] layout) -> in-order lgkm ->
// partial waits -> cross-iteration pipelining. Reads per-kx (small VGPR
// footprint, no R16-style spill).
template <int NO, int CHS, int ROWW>
__device__ __forceinline__ void kconv_plain(
    const uint4* bas, const unsigned short* slu,
    const uint4* wS, const float* wB,
    int y0, int x0, float (&acc)[NO]) {
  const uint4* wp = wS;
  const float* bp = wB;
  int baC = y0 * ROWW + x0;
  #pragma unroll 1
  for (int c = 0; c < 5; ++c) {
    int ba = baC;
    #pragma unroll 1
    for (int ky = 0; ky < 3; ++ky) {
      uint4 q0 = bas[ba], q1 = bas[ba + 1], q2 = bas[ba + 2];
      float s0 = h2f(slu[ba]), s1 = h2f(slu[ba + 1]), s2 = h2f(slu[ba + 2]);
      #pragma unroll
      for (int kx = 0; kx < 3; ++kx) {
        uint4 q = (kx == 0) ? q0 : ((kx == 1) ? q1 : q2);
        float sl = (kx == 0) ? s0 : ((kx == 1) ? s1 : s2);
        h2 a0 = u2h(q.x), a1 = u2h(q.y), a2 = u2h(q.z), a3 = u2h(q.w);
        #pragma unroll
        for (int j = 0; j < NO; ++j) {
          uint4 w = wp[kx * NO + j];
          float a = acc[j];
          a = fdot2(a0, u2h(w.x), a);
          a = fdot2(a1, u2h(w.y), a);
          a = fdot2(a2, u2h(w.z), a);
          a = fdot2(a3, u2h(w.w), a);
          acc[j] = fmaf(sl, bp[kx * NO + j], a);
        }
      }
      wp += 3 * NO; bp += 3 * NO;
      ba += ROWW;
    }
    baC += CHS;
  }
}

// ---------------- prep: conv weights (og-packed) + W1p4 + padded W2 ---------
__global__ __launch_bounds__(256) void k_prep(
    const float* __restrict__ bw1, const float* __restrict__ sw1,
    const float* __restrict__ bw2, const float* __restrict__ sw2,
    const float* __restrict__ bw3, const float* __restrict__ sw3,
    const float* __restrict__ w1, const float* __restrict__ w2,
    unsigned int* __restrict__ V1s, float* __restrict__ V1b,
    unsigned int* __restrict__ V2G0s, float* __restrict__ V2G0b,
    unsigned int* __restrict__ V2G1s, float* __restrict__ V2G1b,
    unsigned int* __restrict__ V3Gs, float* __restrict__ V3Gb,
    unsigned int* __restrict__ W1p4, float* __restrict__ W2p) {
  int t = blockIdx.x * 256 + threadIdx.x;
  if (t < 180) {  // L1: 9 taps x 5 outs x 4 pairs (tap-major, o contiguous)
    int p = t & 3, o = (t >> 2) % 5, in = t / 20;
    V1s[t] = pack2h(sw1[(o * 9 + in) * 8 + 2 * p], sw1[(o * 9 + in) * 8 + 2 * p + 1]);
  }
  if (t < 45)  { int o = t % 5, in = t / 5; V1b[t] = bw1[o * 9 + in]; }
  // L2 og0 (ch 0..2): [cky][kx][j<3] uint4 -> 540 words
  if (t < 540) {
    int p = t & 3, u4 = t >> 2;
    int j = u4 % 3, kx = (u4 / 3) % 3, cky = u4 / 9;
    int in = (cky / 3) * 9 + (cky % 3) * 3 + kx;
    V2G0s[t] = pack2h(sw2[(j * 45 + in) * 8 + 2 * p], sw2[(j * 45 + in) * 8 + 2 * p + 1]);
  }
  if (t < 135) {  // og0 biases
    int j = t % 3, kx = (t / 3) % 3, cky = t / 9;
    int in = (cky / 3) * 9 + (cky % 3) * 3 + kx;
    V2G0b[t] = bw2[j * 45 + in];
  }
  // L2 og1 (ch 3..4): [cky][kx][j<2] uint4 -> 360 words
  if (t < 360) {
    int p = t & 3, u4 = t >> 2;
    int j = u4 % 2, kx = (u4 / 2) % 3, cky = u4 / 6;
    int o = 3 + j;
    int in = (cky / 3) * 9 + (cky % 3) * 3 + kx;
    V2G1s[t] = pack2h(sw2[(o * 45 + in) * 8 + 2 * p], sw2[(o * 45 + in) * 8 + 2 * p + 1]);
  }
  if (t < 90) {   // og1 biases
    int j = t % 2, kx = (t / 2) % 3, cky = t / 6;
    int o = 3 + j;
    int in = (cky / 3) * 9 + (cky % 3) * 3 + kx;
    V2G1b[t] = bw2[o * 45 + in];
  }
  // L3: [ou][cky][kx] uint4 -> 360 words
  if (t < 360) {
    int p = t & 3, u4 = t >> 2;
    int kx = u4 % 3, cky = (u4 / 3) % 15, ou = u4 / 45;
    int in = (cky / 3) * 9 + (cky % 3) * 3 + kx;
    V3Gs[t] = pack2h(sw3[(ou * 45 + in) * 8 + 2 * p], sw3[(ou * 45 + in) * 8 + 2 * p + 1]);
  }
  if (t < 90) {
    int kx = t % 3, cky = (t / 3) % 15, ou = t / 45;
    int in = (cky / 3) * 9 + (cky % 3) * 3 + kx;
    V3Gb[t] = bw3[ou * 45 + in];
  }
  if (t < 43008) {  // W1p4[((g*512)+o)*4+j]: j-th k-pair of group g, out o
    int j = t & 3, o = (t >> 2) & 511, g = t >> 11;
    int kp = g * 4 + j;
    W1p4[t] = (o < 500 && kp < 81)
                  ? pack2h(w1[o * 162 + 2 * kp], w1[o * 162 + 2 * kp + 1])
                  : 0u;
  }
  if (t < 5120) {   // W2p[10][512] zero-padded
    int o = t >> 9, k = t & 511;
    W2p[t] = (k < 500) ? w2[o * 500 + k] : 0.0f;
  }
}

// ---------------- the fused per-image kernel (four waves per block) ---------
__global__ __launch_bounds__(256, 8) void k_fused(
    const float* __restrict__ x,
    const unsigned int* __restrict__ V1s, const float* __restrict__ V1b,
    const unsigned int* __restrict__ V2G0s, const float* __restrict__ V2G0b,
    const unsigned int* __restrict__ V2G1s, const float* __restrict__ V2G1b,
    const unsigned int* __restrict__ V3Gs, const float* __restrict__ V3Gb,
    const unsigned int* __restrict__ W1p4, const float* __restrict__ W2p,
    const float* __restrict__ b1, const float* __restrict__ b2,
    float* __restrict__ out) {
  __shared__ uint4 bas[845];               // 13,520 B
  __shared__ unsigned short slu16[848];    //  1,696 B
  __shared__ float red[40];                // fc2 cross-wave scratch
  // conv2/conv3 weights staged in LDS (6,300 B), wave-uniform broadcast reads
  __shared__ __align__(16) unsigned int sW2G0[540];
  __shared__ __align__(16) unsigned int sW2G1[360];
  __shared__ __align__(16) unsigned int sW3G[360];
  __shared__ float sB2G0[135];
  __shared__ float sB2G1[90];
  __shared__ float sB3G[90];
  float*        basF = (float*)bas;        // dword view of bas
  float*        h3f  = basF + 2048;        // h3 (162 f), dead-by-order region
  unsigned int* hpk  = (unsigned int*)basF + 2560;  // 84 uints
  const int b = blockIdx.x;
  const int tid = threadIdx.x;             // 0..255, four waves

  // P0: stage conv2/conv3 weights into LDS (coalesced; covered by P1 barrier)
  #pragma unroll
  for (int i = tid; i < 540; i += 256) sW2G0[i] = V2G0s[i];
  #pragma unroll
  for (int i = tid; i < 360; i += 256) { sW2G1[i] = V2G1s[i]; sW3G[i] = V3Gs[i]; }
  if (tid < 135) sB2G0[tid] = V2G0b[tid];
  if (tid < 90)  { sB2G1[tid] = V2G1b[tid]; sB3G[tid] = V3Gb[tid]; }

  // P1: featurize input image (784 px), PARITY-SWIZZLED columns:
  //   col xx stored at (xx&1)*14 + (xx>>1)  -> conv1 reads stride-16B
  #pragma unroll 1
  for (int l = tid; l < 784; l += 256) {
    uint4 bs; float sl;
    featurize_regs(x[b * 784 + l], bs, sl);
    int y = l / 28, xx = l - y * 28;
    int idx = y * 28 + ((xx & 1) ? 14 : 0) + (xx >> 1);
    bas[idx] = bs; slu16[idx] = f2h_bits(sl);
  }
  __syncthreads();

  // P2: conv1 (1->5) + 2x2 maxpool; one pooled output per lane (tid<169).
  // SMEM tap-outer path (9 coalesced drains). Parity layout: per ky 8
  // dedup'd reads; kx unrolled (compile-time parity column select).
  float h1v[5];
  if (tid < 169) {
    int py = tid / 13, px = tid % 13;
    float wacc[4][5];
    #pragma unroll
    for (int wi = 0; wi < 4; ++wi)
      #pragma unroll
      for (int o = 0; o < 5; ++o) wacc[wi][o] = 0.0f;
    #pragma unroll 1
    for (int ky = 0; ky < 3; ++ky) {
      int rA = (2 * py + ky) * 28 + px;
      uint4 q[2][4]; float sl[2][4];
      #pragma unroll
      for (int r = 0; r < 2; ++r) {
        int base = rA + r * 28;
        q[r][0] = bas[base];      sl[r][0] = h2f(slu16[base]);       // E0
        q[r][1] = bas[base + 14]; sl[r][1] = h2f(slu16[base + 14]);  // O0
        q[r][2] = bas[base + 1];  sl[r][2] = h2f(slu16[base + 1]);   // E1
        q[r][3] = bas[base + 15]; sl[r][3] = h2f(slu16[base + 15]);  // O1
      }
      const unsigned int* wrow = V1s + ky * 60;
      const float* brow = V1b + ky * 15;
      #pragma unroll
      for (int kx = 0; kx < 3; ++kx) {
        const int cA = (kx == 0) ? 0 : ((kx == 1) ? 1 : 2);
        const int cB = (kx == 0) ? 1 : ((kx == 1) ? 2 : 3);
        const unsigned int* wp = wrow + kx * 20;
        const float* bp = brow + kx * 5;
        #pragma unroll
        for (int dy = 0; dy < 2; ++dy) {
          #pragma unroll
          for (int dx = 0; dx < 2; ++dx) {
            const int ci = dx ? cB : cA;
            uint4 qq = q[dy][ci];
            float s = sl[dy][ci];
            h2 a0 = u2h(qq.x), a1 = u2h(qq.y), a2 = u2h(qq.z), a3 = u2h(qq.w);
            #pragma unroll
            for (int o = 0; o < 5; ++o) {
              float a = wacc[dy * 2 + dx][o];
              a = fdot2(a0, u2h(wp[o * 4 + 0]), a);
              a = fdot2(a1, u2h(wp[o * 4 + 1]), a);
              a = fdot2(a2, u2h(wp[o * 4 + 2]), a);
              a = fdot2(a3, u2h(wp[o * 4 + 3]), a);
              wacc[dy * 2 + dx][o] = fmaf(s, bp[o], a);
            }
          }
        }
      }
    }
    #pragma unroll
    for (int o = 0; o < 5; ++o)
      h1v[o] = fmaxf(fmaxf(wacc[0][o], wacc[1][o]),
                     fmaxf(wacc[2][o], wacc[3][o]));
  }
  __syncthreads();  // all conv1 LDS reads (all waves) done
  // write featurized h1 (aliases the input-pixel region; plain layout)
  if (tid < 169) {
    #pragma unroll
    for (int o = 0; o < 5; ++o) {
      uint4 bs; float sl;
      featurize_regs(h1v[o], bs, sl);
      bas[o * 169 + tid] = bs; slu16[o * 169 + tid] = f2h_bits(sl);
    }
  }
  __syncthreads();

  // P4: conv2 (5->5); lanes split by (position, channel-group):
  //   og=0 (waves 0,1): channels 0..2   og=1 (waves 2,3): channels 3..4
  // Weights from LDS -> in-order lgkm -> pipelined partial waits.
  int og = __builtin_amdgcn_readfirstlane(tid >> 7);   // wave-uniform
  int p2 = tid & 127;
  float acc2a[3] = {0.0f, 0.0f, 0.0f};
  float acc2b[2] = {0.0f, 0.0f};
  {
    int pc = (p2 < 121) ? p2 : 120;     // clamp (writeback guarded)
    int y0 = pc / 11, x0 = pc % 11;
    if (og == 0)
      kconv_plain<3, 169, 13>(bas, slu16, (const uint4*)sW2G0, sB2G0, y0, x0, acc2a);
    else
      kconv_plain<2, 169, 13>(bas, slu16, (const uint4*)sW2G1, sB2G1, y0, x0, acc2b);
  }
  __syncthreads();  // all conv2 reads done before h2 overwrites bas
  if (p2 < 121) {
    if (og == 0) {
      #pragma unroll
      for (int j = 0; j < 3; ++j) {
        uint4 bs; float sl;
        featurize_regs(acc2a[j], bs, sl);
        bas[j * 121 + p2] = bs; slu16[j * 121 + p2] = f2h_bits(sl);
      }
    } else {
      #pragma unroll
      for (int j = 0; j < 2; ++j) {
        uint4 bs; float sl;
        featurize_regs(acc2b[j], bs, sl);
        bas[(3 + j) * 121 + p2] = bs; slu16[(3 + j) * 121 + p2] = f2h_bits(sl);
      }
    }
  }
  __syncthreads();

  // P6: conv3 (5->2); lanes split by (position, output):
  //   waves 0,1: out 0   waves 2,3: out 1. Weights from LDS.
  float acc3[1] = {0.0f};
  {
    int pc = (p2 < 81) ? p2 : 80;
    int y0 = pc / 9, x0 = pc - (pc / 9) * 9;
    kconv_plain<1, 121, 11>(bas, slu16, (const uint4*)sW3G + og * 45,
                            sB3G + og * 45, y0, x0, acc3);
  }
  __syncthreads();  // all conv3 reads done before h3 overwrites bas region
  if (p2 < 81) h3f[og * 81 + p2] = acc3[0];
  __syncthreads();
  if (tid < 84)
    hpk[tid] = (tid < 81) ? pack2h(h3f[2 * tid], h3f[2 * tid + 1]) : 0u;
  __syncthreads();

  // P7: fc1 (162->500) + bias + ReLU; 2 outs/lane; double-buffered global
  // loads (vmcnt is in-order & separate from LDS lgkmcnt -> real prefetch).
  float fa[2] = {0.0f, 0.0f};
  {
    const uint4* hp4 = (const uint4*)hpk;
    const uint4* wbase = (const uint4*)W1p4 + tid;
    uint4 wA[2], wB[2];
    #pragma unroll
    for (int i = 0; i < 2; ++i) wA[i] = wbase[i * 256];   // group 0
    #pragma unroll 1
    for (int g = 0; g < 21; g += 2) {
      if (g + 1 < 21) {
        const uint4* p = wbase + (g + 1) * 512;
        #pragma unroll
        for (int i = 0; i < 2; ++i) wB[i] = p[i * 256];
      }
      {
        uint4 hk = hp4[g];
        #pragma unroll
        for (int i = 0; i < 2; ++i) {
          float a = fa[i];
          a = fdot2(u2h(hk.x), u2h(wA[i].x), a);
          a = fdot2(u2h(hk.y), u2h(wA[i].y), a);
          a = fdot2(u2h(hk.z), u2h(wA[i].z), a);
          a = fdot2(u2h(hk.w), u2h(wA[i].w), a);
          fa[i] = a;
        }
      }
      if (g + 2 < 21) {
        const uint4* p = wbase + (g + 2) * 512;
        #pragma unroll
        for (int i = 0; i < 2; ++i) wA[i] = p[i * 256];
      }
      if (g + 1 < 21) {
        uint4 hk = hp4[g + 1];
        #pragma unroll
        for (int i = 0; i < 2; ++i) {
          float a = fa[i];
          a = fdot2(u2h(hk.x), u2h(wB[i].x), a);
          a = fdot2(u2h(hk.y), u2h(wB[i].y), a);
          a = fdot2(u2h(hk.z), u2h(wB[i].z), a);
          a = fdot2(u2h(hk.w), u2h(wB[i].w), a);
          fa[i] = a;
        }
      }
    }
  }
  #pragma unroll
  for (int i = 0; i < 2; ++i) {
    int o = tid + 256 * i;
    float bb = (o < 500) ? b1[o] : 0.0f;
    float v = fa[i] + bb;
    basF[o] = (v > 0.0f && o < 500) ? v : 0.0f;  // fc1out[512] in bas[0..127]
  }
  __syncthreads();

  // P8: fc2 (500->10): lane covers k = 2*tid..2*tid+1, shfl + LDS reduction
  float acc10[10];
  {
    float2 ha = ((const float2*)basF)[tid];
    #pragma unroll
    for (int o = 0; o < 10; ++o) {
      float2 w = ((const float2*)&W2p[o * 512])[tid];
      acc10[o] = ha.x * w.x + ha.y * w.y;
    }
  }
  #pragma unroll
  for (int off = 32; off > 0; off >>= 1) {
    #pragma unroll
    for (int o = 0; o < 10; ++o) acc10[o] += __shfl_down(acc10[o], off);
  }
  if ((tid & 63) == 0) {
    int wid = tid >> 6;
    #pragma unroll
    for (int o = 0; o < 10; ++o) red[wid * 10 + o] = acc10[o];
  }
  __syncthreads();
  if (tid < 10)
    out[b * 10 + tid] = red[tid] + red[10 + tid] + red[20 + tid] + red[30 + tid] + b2[tid];
}

// ---------------------------------------------------------------------------
extern "C" void kernel_launch(void* const* d_in, const int* in_sizes, int n_in,
                              void* d_out, int out_size, void* d_ws, size_t ws_size,
                              hipStream_t stream) {
  (void)in_sizes; (void)n_in; (void)out_size; (void)ws_size;
  const float* x   = (const float*)d_in[0];
  const float* bw1 = (const float*)d_in[1];
  const float* sw1 = (const float*)d_in[2];
  const float* bw2 = (const float*)d_in[3];
  const float* sw2 = (const float*)d_in[4];
  const float* bw3 = (const float*)d_in[5];
  const float* sw3 = (const float*)d_in[6];
  const float* w1  = (const float*)d_in[7];
  const float* b1  = (const float*)d_in[8];
  const float* w2  = (const float*)d_in[9];
  const float* b2  = (const float*)d_in[10];
  float* out = (float*)d_out;

  char* ws = (char*)d_ws;
  unsigned int* V1s   = (unsigned int*)(ws);           // 180 u   (720 B)
  float*        V1b   = (float*)(ws + 768);            // 45 f    (180 B)
  unsigned int* V2G0s = (unsigned int*)(ws + 1024);    // 540 u   (2,160 B)
  unsigned int* V2G1s = (unsigned int*)(ws + 3200);    // 360 u   (1,440 B)
  unsigned int* V3Gs  = (unsigned int*)(ws + 4640);    // 360 u   (1,440 B)
  float*        V2G0b = (float*)(ws + 6080);           // 135 f   (540 B)
  float*        V2G1b = (float*)(ws + 6624);           // 90 f    (360 B)
  float*        V3Gb  = (float*)(ws + 6984);           // 90 f    (360 B)
  float*        W2p   = (float*)(ws + 7680);           // 5,120 f (20,480 B)
  unsigned int* W1p4  = (unsigned int*)(ws + 28672);   // 43,008 u (172,032 B)

  k_prep<<<168, 256, 0, stream>>>(bw1, sw1, bw2, sw2, bw3, sw3, w1, w2,
                                  V1s, V1b, V2G0s, V2G0b, V2G1s, V2G1b,
                                  V3Gs, V3Gb, W1p4, W2p);
  k_fused<<<2048, 256, 0, stream>>>(x, V1s, V1b, V2G0s, V2G0b, V2G1s, V2G1b,
                                    V3Gs, V3Gb, W1p4, W2p, b1, b2, out);
}

// Round 10
// 128.485 us; speedup vs baseline: 1.0507x; 1.0507x over previous
//
#include <hip/hip_runtime.h>

// ---------------------------------------------------------------------------
// R23 = R21 restored (best measured: k_fused 58.4-58.6us, bench 127.5us).
// Session-final. Measured dead ends (do not revisit without new evidence):
//  - occupancy: 2-wave->4-wave flat (duration = VALU-work / VALUBusy ~62%,
//    issue-port bound, extra waves don't raise issue rate)
//  - weights-in-LDS: regression BOTH times (R16 spill; R22 clean: -12%,
//    occupancy 57->46%, ds_read issue slots cost more than SMEM drains)
//  - manual LDS prefetch: compiler sinks the loads back (R17)
//  - MFMA for the convs: tiles 5-16 cols of 16 -> util<=10%, scaffolding
//    exceeds MAC savings (R19 flat, R20 -17%)
//  - bank-conflict fixes: parity swizzle moved conflicts but not time (R21)
// Structure: one block = one image, 4 waves; conv1 tap-outer SMEM weights;
// conv2/conv3 og-split channel groups, og-contiguous SMEM weight rows;
// fc1 double-buffered global loads; fc2 shfl+LDS reduce.
// Cardinal cubic B-spline: basis_j(x) = B3(u - j), u = 2.5x+5.5 (4 taps).
// ---------------------------------------------------------------------------

typedef _Float16 h2 __attribute__((ext_vector_type(2)));

__device__ __forceinline__ h2 u2h(unsigned int u) {
  union { unsigned int x; h2 h; } v; v.x = u; return v.h;
}
__device__ __forceinline__ unsigned short f2h_bits(float x) {
  union { _Float16 h; unsigned short u; } v; v.h = (_Float16)x; return v.u;
}
__device__ __forceinline__ float h2f(unsigned short u) {
  union { unsigned short u; _Float16 h; } v; v.u = u; return (float)v.h;
}
__device__ __forceinline__ unsigned int pack2h(float a, float b) {
  return (unsigned int)f2h_bits(a) | ((unsigned int)f2h_bits(b) << 16);
}
__device__ __forceinline__ float fdot2(h2 a, h2 b, float c) {
  return __builtin_amdgcn_fdot2(a, b, c, false);
}

// Basis window (8 f16 packed in uint4) + silu, all in registers.
__device__ __forceinline__ void featurize_regs(float v, uint4& bs, float& silu) {
  silu = v * __builtin_amdgcn_rcpf(1.0f + __expf(-v));
  bs.x = 0u; bs.y = 0u; bs.z = 0u; bs.w = 0u;
  float u = fmaf(v, 2.5f, 5.5f);
  if (u >= 0.0f && u < 11.0f) {
    float tf = floorf(u);
    float f = u - tf, f2 = f * f, f3 = f2 * f, om = 1.0f - f;
    const float c6 = 1.0f / 6.0f;
    float w0 = om * om * om * c6;
    float w1 = (3.0f * f3 - 6.0f * f2 + 4.0f) * c6;
    float w2 = (-3.0f * f3 + 3.0f * f2 + 3.0f * f + 1.0f) * c6;
    float w3 = f3 * c6;
    unsigned long long w01 =
        (unsigned long long)f2h_bits(w0) |
        ((unsigned long long)f2h_bits(w1) << 16) |
        ((unsigned long long)f2h_bits(w2) << 32) |
        ((unsigned long long)f2h_bits(w3) << 48);
    int t = (int)tf;                 // 0..10; window starts at slot t-3
    int s = 16 * t - 48;             // bit shift into 128-bit field
    unsigned long long lo, hi;
    if (s >= 0) {
      lo = (s < 64) ? (w01 << s) : 0ull;
      hi = (s == 0) ? 0ull : ((s < 64) ? (w01 >> (64 - s)) : (w01 << (s - 64)));
    } else {
      lo = w01 >> (-s);
      hi = 0ull;
    }
    bs.x = (unsigned int)lo; bs.y = (unsigned int)(lo >> 32);
    bs.z = (unsigned int)hi; bs.w = (unsigned int)(hi >> 32);
  }
}

// KAN 3x3-conv accumulation, one position per lane, NO output channels.
// Weights (wS/wB) are og-contiguous global arrays laid out [cky][kx][j] ->
// one wide s_load per cky row -> SGPR operands.
template <int NO, int CHS, int ROWW>
__device__ __forceinline__ void kconv_plain(
    const uint4* bas, const unsigned short* slu,
    const uint4* __restrict__ wS, const float* __restrict__ wB,
    int y0, int x0, float (&acc)[NO]) {
  const uint4* wp = wS;
  const float* bp = wB;
  int baC = y0 * ROWW + x0;
  #pragma unroll 1
  for (int c = 0; c < 5; ++c) {
    int ba = baC;
    #pragma unroll 1
    for (int ky = 0; ky < 3; ++ky) {
      uint4 q0 = bas[ba], q1 = bas[ba + 1], q2 = bas[ba + 2];
      float s0 = h2f(slu[ba]), s1 = h2f(slu[ba + 1]), s2 = h2f(slu[ba + 2]);
      #pragma unroll
      for (int kx = 0; kx < 3; ++kx) {
        uint4 q = (kx == 0) ? q0 : ((kx == 1) ? q1 : q2);
        float sl = (kx == 0) ? s0 : ((kx == 1) ? s1 : s2);
        h2 a0 = u2h(q.x), a1 = u2h(q.y), a2 = u2h(q.z), a3 = u2h(q.w);
        #pragma unroll
        for (int j = 0; j < NO; ++j) {
          uint4 w = wp[kx * NO + j];
          float a = acc[j];
          a = fdot2(a0, u2h(w.x), a);
          a = fdot2(a1, u2h(w.y), a);
          a = fdot2(a2, u2h(w.z), a);
          a = fdot2(a3, u2h(w.w), a);
          acc[j] = fmaf(sl, bp[kx * NO + j], a);
        }
      }
      wp += 3 * NO; bp += 3 * NO;
      ba += ROWW;
    }
    baC += CHS;
  }
}

// ---------------- prep: conv weights (og-packed) + W1p4 + padded W2 ---------
__global__ __launch_bounds__(256) void k_prep(
    const float* __restrict__ bw1, const float* __restrict__ sw1,
    const float* __restrict__ bw2, const float* __restrict__ sw2,
    const float* __restrict__ bw3, const float* __restrict__ sw3,
    const float* __restrict__ w1, const float* __restrict__ w2,
    unsigned int* __restrict__ V1s, float* __restrict__ V1b,
    unsigned int* __restrict__ V2G0s, float* __restrict__ V2G0b,
    unsigned int* __restrict__ V2G1s, float* __restrict__ V2G1b,
    unsigned int* __restrict__ V3Gs, float* __restrict__ V3Gb,
    unsigned int* __restrict__ W1p4, float* __restrict__ W2p) {
  int t = blockIdx.x * 256 + threadIdx.x;
  if (t < 180) {  // L1: 9 taps x 5 outs x 4 pairs (tap-major, o contiguous)
    int p = t & 3, o = (t >> 2) % 5, in = t / 20;
    V1s[t] = pack2h(sw1[(o * 9 + in) * 8 + 2 * p], sw1[(o * 9 + in) * 8 + 2 * p + 1]);
  }
  if (t < 45)  { int o = t % 5, in = t / 5; V1b[t] = bw1[o * 9 + in]; }
  // L2 og0 (ch 0..2): [cky][kx][j<3] uint4 -> 540 words
  if (t < 540) {
    int p = t & 3, u4 = t >> 2;
    int j = u4 % 3, kx = (u4 / 3) % 3, cky = u4 / 9;
    int in = (cky / 3) * 9 + (cky % 3) * 3 + kx;
    V2G0s[t] = pack2h(sw2[(j * 45 + in) * 8 + 2 * p], sw2[(j * 45 + in) * 8 + 2 * p + 1]);
  }
  if (t < 135) {  // og0 biases
    int j = t % 3, kx = (t / 3) % 3, cky = t / 9;
    int in = (cky / 3) * 9 + (cky % 3) * 3 + kx;
    V2G0b[t] = bw2[j * 45 + in];
  }
  // L2 og1 (ch 3..4): [cky][kx][j<2] uint4 -> 360 words
  if (t < 360) {
    int p = t & 3, u4 = t >> 2;
    int j = u4 % 2, kx = (u4 / 2) % 3, cky = u4 / 6;
    int o = 3 + j;
    int in = (cky / 3) * 9 + (cky % 3) * 3 + kx;
    V2G1s[t] = pack2h(sw2[(o * 45 + in) * 8 + 2 * p], sw2[(o * 45 + in) * 8 + 2 * p + 1]);
  }
  if (t < 90) {   // og1 biases
    int j = t % 2, kx = (t / 2) % 3, cky = t / 6;
    int o = 3 + j;
    int in = (cky / 3) * 9 + (cky % 3) * 3 + kx;
    V2G1b[t] = bw2[o * 45 + in];
  }
  // L3: [ou][cky][kx] uint4 -> 360 words
  if (t < 360) {
    int p = t & 3, u4 = t >> 2;
    int kx = u4 % 3, cky = (u4 / 3) % 15, ou = u4 / 45;
    int in = (cky / 3) * 9 + (cky % 3) * 3 + kx;
    V3Gs[t] = pack2h(sw3[(ou * 45 + in) * 8 + 2 * p], sw3[(ou * 45 + in) * 8 + 2 * p + 1]);
  }
  if (t < 90) {
    int kx = t % 3, cky = (t / 3) % 15, ou = t / 45;
    int in = (cky / 3) * 9 + (cky % 3) * 3 + kx;
    V3Gb[t] = bw3[ou * 45 + in];
  }
  if (t < 43008) {  // W1p4[((g*512)+o)*4+j]: j-th k-pair of group g, out o
    int j = t & 3, o = (t >> 2) & 511, g = t >> 11;
    int kp = g * 4 + j;
    W1p4[t] = (o < 500 && kp < 81)
                  ? pack2h(w1[o * 162 + 2 * kp], w1[o * 162 + 2 * kp + 1])
                  : 0u;
  }
  if (t < 5120) {   // W2p[10][512] zero-padded
    int o = t >> 9, k = t & 511;
    W2p[t] = (k < 500) ? w2[o * 500 + k] : 0.0f;
  }
}

// ---------------- the fused per-image kernel (four waves per block) ---------
__global__ __launch_bounds__(256, 8) void k_fused(
    const float* __restrict__ x,
    const unsigned int* __restrict__ V1s, const float* __restrict__ V1b,
    const unsigned int* __restrict__ V2G0s, const float* __restrict__ V2G0b,
    const unsigned int* __restrict__ V2G1s, const float* __restrict__ V2G1b,
    const unsigned int* __restrict__ V3Gs, const float* __restrict__ V3Gb,
    const unsigned int* __restrict__ W1p4, const float* __restrict__ W2p,
    const float* __restrict__ b1, const float* __restrict__ b2,
    float* __restrict__ out) {
  __shared__ uint4 bas[845];               // 13,520 B
  __shared__ unsigned short slu16[848];    //  1,696 B
  __shared__ float red[40];                // fc2 cross-wave scratch
  float*        basF = (float*)bas;        // dword view of bas
  float*        h3f  = basF + 2048;        // h3 (162 f), dead-by-order region
  unsigned int* hpk  = (unsigned int*)basF + 2560;  // 84 uints
  const int b = blockIdx.x;
  const int tid = threadIdx.x;             // 0..255, four waves

  // P1: featurize input image (784 px), PARITY-SWIZZLED columns:
  //   col xx stored at (xx&1)*14 + (xx>>1)  -> conv1 reads stride-16B
  #pragma unroll 1
  for (int l = tid; l < 784; l += 256) {
    uint4 bs; float sl;
    featurize_regs(x[b * 784 + l], bs, sl);
    int y = l / 28, xx = l - y * 28;
    int idx = y * 28 + ((xx & 1) ? 14 : 0) + (xx >> 1);
    bas[idx] = bs; slu16[idx] = f2h_bits(sl);
  }
  __syncthreads();

  // P2: conv1 (1->5) + 2x2 maxpool; one pooled output per lane (tid<169).
  // Per ky: 8 dedup'd parity reads (rows ky,ky+1; parity-cols E0,O0,E1,O1),
  // kx UNROLLED (parity col-select compile-time):
  //   kx=0 -> (E0,O0)  kx=1 -> (O0,E1)  kx=2 -> (E1,O1)
  float h1v[5];
  if (tid < 169) {
    int py = tid / 13, px = tid % 13;
    float wacc[4][5];
    #pragma unroll
    for (int wi = 0; wi < 4; ++wi)
      #pragma unroll
      for (int o = 0; o < 5; ++o) wacc[wi][o] = 0.0f;
    #pragma unroll 1
    for (int ky = 0; ky < 3; ++ky) {
      int rA = (2 * py + ky) * 28 + px;
      uint4 q[2][4]; float sl[2][4];
      #pragma unroll
      for (int r = 0; r < 2; ++r) {
        int base = rA + r * 28;
        q[r][0] = bas[base];      sl[r][0] = h2f(slu16[base]);       // E0
        q[r][1] = bas[base + 14]; sl[r][1] = h2f(slu16[base + 14]);  // O0
        q[r][2] = bas[base + 1];  sl[r][2] = h2f(slu16[base + 1]);   // E1
        q[r][3] = bas[base + 15]; sl[r][3] = h2f(slu16[base + 15]);  // O1
      }
      const unsigned int* wrow = V1s + ky * 60;
      const float* brow = V1b + ky * 15;
      #pragma unroll
      for (int kx = 0; kx < 3; ++kx) {
        const int cA = (kx == 0) ? 0 : ((kx == 1) ? 1 : 2);
        const int cB = (kx == 0) ? 1 : ((kx == 1) ? 2 : 3);
        const unsigned int* wp = wrow + kx * 20;
        const float* bp = brow + kx * 5;
        #pragma unroll
        for (int dy = 0; dy < 2; ++dy) {
          #pragma unroll
          for (int dx = 0; dx < 2; ++dx) {
            const int ci = dx ? cB : cA;
            uint4 qq = q[dy][ci];
            float s = sl[dy][ci];
            h2 a0 = u2h(qq.x), a1 = u2h(qq.y), a2 = u2h(qq.z), a3 = u2h(qq.w);
            #pragma unroll
            for (int o = 0; o < 5; ++o) {
              float a = wacc[dy * 2 + dx][o];
              a = fdot2(a0, u2h(wp[o * 4 + 0]), a);
              a = fdot2(a1, u2h(wp[o * 4 + 1]), a);
              a = fdot2(a2, u2h(wp[o * 4 + 2]), a);
              a = fdot2(a3, u2h(wp[o * 4 + 3]), a);
              wacc[dy * 2 + dx][o] = fmaf(s, bp[o], a);
            }
          }
        }
      }
    }
    #pragma unroll
    for (int o = 0; o < 5; ++o)
      h1v[o] = fmaxf(fmaxf(wacc[0][o], wacc[1][o]),
                     fmaxf(wacc[2][o], wacc[3][o]));
  }
  __syncthreads();  // all conv1 LDS reads (all waves) done
  // write featurized h1 (aliases the input-pixel region; plain layout)
  if (tid < 169) {
    #pragma unroll
    for (int o = 0; o < 5; ++o) {
      uint4 bs; float sl;
      featurize_regs(h1v[o], bs, sl);
      bas[o * 169 + tid] = bs; slu16[o * 169 + tid] = f2h_bits(sl);
    }
  }
  __syncthreads();

  // P4: conv2 (5->5); lanes split by (position, channel-group):
  //   og=0 (waves 0,1): channels 0..2   og=1 (waves 2,3): channels 3..4
  int og = __builtin_amdgcn_readfirstlane(tid >> 7);   // wave-uniform
  int p2 = tid & 127;
  float acc2a[3] = {0.0f, 0.0f, 0.0f};
  float acc2b[2] = {0.0f, 0.0f};
  {
    int pc = (p2 < 121) ? p2 : 120;     // clamp (writeback guarded)
    int y0 = pc / 11, x0 = pc % 11;
    if (og == 0)
      kconv_plain<3, 169, 13>(bas, slu16, (const uint4*)V2G0s, V2G0b, y0, x0, acc2a);
    else
      kconv_plain<2, 169, 13>(bas, slu16, (const uint4*)V2G1s, V2G1b, y0, x0, acc2b);
  }
  __syncthreads();  // all conv2 reads done before h2 overwrites bas
  if (p2 < 121) {
    if (og == 0) {
      #pragma unroll
      for (int j = 0; j < 3; ++j) {
        uint4 bs; float sl;
        featurize_regs(acc2a[j], bs, sl);
        bas[j * 121 + p2] = bs; slu16[j * 121 + p2] = f2h_bits(sl);
      }
    } else {
      #pragma unroll
      for (int j = 0; j < 2; ++j) {
        uint4 bs; float sl;
        featurize_regs(acc2b[j], bs, sl);
        bas[(3 + j) * 121 + p2] = bs; slu16[(3 + j) * 121 + p2] = f2h_bits(sl);
      }
    }
  }
  __syncthreads();

  // P6: conv3 (5->2); lanes split by (position, output):
  //   waves 0,1: out 0   waves 2,3: out 1
  float acc3[1] = {0.0f};
  {
    int pc = (p2 < 81) ? p2 : 80;
    int y0 = pc / 9, x0 = pc - (pc / 9) * 9;
    kconv_plain<1, 121, 11>(bas, slu16, (const uint4*)V3Gs + og * 45,
                            V3Gb + og * 45, y0, x0, acc3);
  }
  __syncthreads();  // all conv3 reads done before h3 overwrites bas region
  if (p2 < 81) h3f[og * 81 + p2] = acc3[0];
  __syncthreads();
  if (tid < 84)
    hpk[tid] = (tid < 81) ? pack2h(h3f[2 * tid], h3f[2 * tid + 1]) : 0u;
  __syncthreads();

  // P7: fc1 (162->500) + bias + ReLU; 2 outs/lane; double-buffered global
  // loads (vmcnt is in-order & separate from LDS lgkmcnt -> real prefetch).
  float fa[2] = {0.0f, 0.0f};
  {
    const uint4* hp4 = (const uint4*)hpk;
    const uint4* wbase = (const uint4*)W1p4 + tid;
    uint4 wA[2], wB[2];
    #pragma unroll
    for (int i = 0; i < 2; ++i) wA[i] = wbase[i * 256];   // group 0
    #pragma unroll 1
    for (int g = 0; g < 21; g += 2) {
      if (g + 1 < 21) {
        const uint4* p = wbase + (g + 1) * 512;
        #pragma unroll
        for (int i = 0; i < 2; ++i) wB[i] = p[i * 256];
      }
      {
        uint4 hk = hp4[g];
        #pragma unroll
        for (int i = 0; i < 2; ++i) {
          float a = fa[i];
          a = fdot2(u2h(hk.x), u2h(wA[i].x), a);
          a = fdot2(u2h(hk.y), u2h(wA[i].y), a);
          a = fdot2(u2h(hk.z), u2h(wA[i].z), a);
          a = fdot2(u2h(hk.w), u2h(wA[i].w), a);
          fa[i] = a;
        }
      }
      if (g + 2 < 21) {
        const uint4* p = wbase + (g + 2) * 512;
        #pragma unroll
        for (int i = 0; i < 2; ++i) wA[i] = p[i * 256];
      }
      if (g + 1 < 21) {
        uint4 hk = hp4[g + 1];
        #pragma unroll
        for (int i = 0; i < 2; ++i) {
          float a = fa[i];
          a = fdot2(u2h(hk.x), u2h(wB[i].x), a);
          a = fdot2(u2h(hk.y), u2h(wB[i].y), a);
          a = fdot2(u2h(hk.z), u2h(wB[i].z), a);
          a = fdot2(u2h(hk.w), u2h(wB[i].w), a);
          fa[i] = a;
        }
      }
    }
  }
  #pragma unroll
  for (int i = 0; i < 2; ++i) {
    int o = tid + 256 * i;
    float bb = (o < 500) ? b1[o] : 0.0f;
    float v = fa[i] + bb;
    basF[o] = (v > 0.0f && o < 500) ? v : 0.0f;  // fc1out[512] in bas[0..127]
  }
  __syncthreads();

  // P8: fc2 (500->10): lane covers k = 2*tid..2*tid+1, shfl + LDS reduction
  float acc10[10];
  {
    float2 ha = ((const float2*)basF)[tid];
    #pragma unroll
    for (int o = 0; o < 10; ++o) {
      float2 w = ((const float2*)&W2p[o * 512])[tid];
      acc10[o] = ha.x * w.x + ha.y * w.y;
    }
  }
  #pragma unroll
  for (int off = 32; off > 0; off >>= 1) {
    #pragma unroll
    for (int o = 0; o < 10; ++o) acc10[o] += __shfl_down(acc10[o], off);
  }
  if ((tid & 63) == 0) {
    int wid = tid >> 6;
    #pragma unroll
    for (int o = 0; o < 10; ++o) red[wid * 10 + o] = acc10[o];
  }
  __syncthreads();
  if (tid < 10)
    out[b * 10 + tid] = red[tid] + red[10 + tid] + red[20 + tid] + red[30 + tid] + b2[tid];
}

// ---------------------------------------------------------------------------
extern "C" void kernel_launch(void* const* d_in, const int* in_sizes, int n_in,
                              void* d_out, int out_size, void* d_ws, size_t ws_size,
                              hipStream_t stream) {
  (void)in_sizes; (void)n_in; (void)out_size; (void)ws_size;
  const float* x   = (const float*)d_in[0];
  const float* bw1 = (const float*)d_in[1];
  const float* sw1 = (const float*)d_in[2];
  const float* bw2 = (const float*)d_in[3];
  const float* sw2 = (const float*)d_in[4];
  const float* bw3 = (const float*)d_in[5];
  const float* sw3 = (const float*)d_in[6];
  const float* w1  = (const float*)d_in[7];
  const float* b1  = (const float*)d_in[8];
  const float* w2  = (const float*)d_in[9];
  const float* b2  = (const float*)d_in[10];
  float* out = (float*)d_out;

  char* ws = (char*)d_ws;
  unsigned int* V1s   = (unsigned int*)(ws);           // 180 u   (720 B)
  float*        V1b   = (float*)(ws + 768);            // 45 f    (180 B)
  unsigned int* V2G0s = (unsigned int*)(ws + 1024);    // 540 u   (2,160 B)
  unsigned int* V2G1s = (unsigned int*)(ws + 3200);    // 360 u   (1,440 B)
  unsigned int* V3Gs  = (unsigned int*)(ws + 4640);    // 360 u   (1,440 B)
  float*        V2G0b = (float*)(ws + 6080);           // 135 f   (540 B)
  float*        V2G1b = (float*)(ws + 6624);           // 90 f    (360 B)
  float*        V3Gb  = (float*)(ws + 6984);           // 90 f    (360 B)
  float*        W2p   = (float*)(ws + 7680);           // 5,120 f (20,480 B)
  unsigned int* W1p4  = (unsigned int*)(ws + 28672);   // 43,008 u (172,032 B)

  k_prep<<<168, 256, 0, stream>>>(bw1, sw1, bw2, sw2, bw3, sw3, w1, w2,
                                  V1s, V1b, V2G0s, V2G0b, V2G1s, V2G1b,
                                  V3Gs, V3Gb, W1p4, W2p);
  k_fused<<<2048, 256, 0, stream>>>(x, V1s, V1b, V2G0s, V2G0b, V2G1s, V2G1b,
                                    V3Gs, V3Gb, W1p4, W2p, b1, b2, out);
}